// Round 8
// baseline (705.223 us; speedup 1.0000x reference)
//
#include <hip/hip_runtime.h>
#include <hip/hip_bf16.h>

typedef __attribute__((ext_vector_type(8))) short short8;
typedef __attribute__((ext_vector_type(4))) float f32x4;

#define BN_EPS 1e-5f
#define MROWS 4096
#define CDIM 2048
#define NKT 32   // K tiles of 64

#define SB() __builtin_amdgcn_sched_barrier(0)

__device__ __forceinline__ void gload_lds16(const void* g, void* l) {
  __builtin_amdgcn_global_load_lds(
      (const __attribute__((address_space(1))) void*)g,
      (__attribute__((address_space(3))) void*)l, 16, 0, 0);
}

// ---------------------------------------------------------------------------
// fp32 -> bf16 conversion (vectorized float4 -> ushort4)
// ---------------------------------------------------------------------------
__global__ __launch_bounds__(256) void cvt_f32_bf16(const float* __restrict__ in,
                                                    unsigned short* __restrict__ out,
                                                    int n4) {
  int idx = blockIdx.x * blockDim.x + threadIdx.x;
  int stride = gridDim.x * blockDim.x;
  for (int i = idx; i < n4; i += stride) {
    float4 vv = ((const float4*)in)[i];
    __hip_bfloat16 h0 = __float2bfloat16(vv.x);
    __hip_bfloat16 h1 = __float2bfloat16(vv.y);
    __hip_bfloat16 h2 = __float2bfloat16(vv.z);
    __hip_bfloat16 h3 = __float2bfloat16(vv.w);
    ushort4 o;
    o.x = *(unsigned short*)&h0;
    o.y = *(unsigned short*)&h1;
    o.z = *(unsigned short*)&h2;
    o.w = *(unsigned short*)&h3;
    ((ushort4*)out)[i] = o;
  }
}

// ---------------------------------------------------------------------------
// 128x256 tile, BK=64. A via 3-deep LDS ring (48 KiB, shared x4 across
// wn-waves); B register-direct from global (wave-exclusive up to x2 wm-share,
// K-major layout -> 16-row x 64B coalesced fragment loads), prefetched one
// full K-tile ahead. DS pipe traffic drops 176KB -> 80KB per tile.
// Grid 768 = 3 exact rounds at 1 block/CU. 8 waves (2M x 4N) of 64x64.
// vmcnt ledger at per-tile sync: outstanding = SA(t+1)x2 + B(t+1)x8 ->
// vmcnt(8) retires SA(t+1). SA(t+2) issues AFTER the barrier (2-barrier WAR
// separation on ring slots). B consumed via compiler register deps.
// Swizzle chunk^=(row&7) on 16B chunks (R3/R6-verified, 0 conflicts).
// out[h][m][d] = relu((sum_c A[h][m][c]*W[h][d][c])*scale + shift)
// ---------------------------------------------------------------------------
__global__ __launch_bounds__(512, 2) void gemm_bdir(
    const __hip_bfloat16* __restrict__ A, long long a_hstride,
    const __hip_bfloat16* __restrict__ W,
    const float* __restrict__ gp, const float* __restrict__ bp,
    const float* __restrict__ mp, const float* __restrict__ vp,
    __hip_bfloat16* __restrict__ out)
{
  __shared__ __hip_bfloat16 sm[24576];   // 48 KiB = 3 slots x 8192 elems

  const int tid  = threadIdx.x;
  const int w    = tid >> 6;
  const int lane = tid & 63;

  // XCD-bijective swizzle over 768 blocks (768 % 8 == 0, q = 96)
  const int bid = blockIdx.x;
  const int swz = (bid & 7) * 96 + (bid >> 3);
  const int h   = swz >> 8;          // 256 tiles per head
  const int rem = swz & 255;
  const int mt  = rem >> 3;          // 32 m-tiles of 128
  const int nt  = rem & 7;           // 8 n-tiles of 256

  const __hip_bfloat16* Abase = A + (size_t)h * (size_t)a_hstride + (size_t)(mt * 128) * CDIM;

  // A staging: tile 128x64 = 1024 16B slots; thread t -> slots t, t+512.
  // slot s: row=s>>3, chunk=s&7, global chunk = chunk ^ (row&7).
  const int row0 = tid >> 3;
  const int ch0  = (tid & 7) ^ (row0 & 7);
  const __hip_bfloat16* aSrc = Abase + (size_t)row0 * CDIM + ch0 * 8;

  const int wm = w >> 2, wn = w & 3;
  const int fr = lane & 15, fg = lane >> 4;
  // A fragment read offsets within a slot (swizzled)
  const int offs0 = fr * 64 + ((fg ^ (fr & 7)) << 3);        // ksub 0
  const int offs1 = fr * 64 + (((fg + 4) ^ (fr & 7)) << 3);  // ksub 1

  // B direct: lane (fr,fg) reads row nt*256+wn*64+fr+j*16, col fg*8 (+ks*32).
  // 16 rows x 64B contiguous per instruction -> fully coalesced.
  const __hip_bfloat16* bP = W +
      ((size_t)h * CDIM + (size_t)(nt * 256 + wn * 64 + fr)) * CDIM + fg * 8;

  auto SA_ = [&](int slotOff, int t) {
    __hip_bfloat16* dp = &sm[slotOff + tid * 8];
    gload_lds16(aSrc + t * 64, dp);
    gload_lds16(aSrc + (size_t)64 * CDIM + t * 64, dp + 4096);
  };

  f32x4 acc[4][4] = {};
  short8 Af[4], Ap[4], Bx[4][2], By[4][2];

#define LDA4(dst, base)                                                  \
  _Pragma("unroll") for (int i_ = 0; i_ < 4; ++i_)                       \
    dst[i_] = *(const short8*)&sm[(base) + i_ * 1024];

#define ISSUE_B(Bset, t1)                                                \
  _Pragma("unroll") for (int j_ = 0; j_ < 4; ++j_) {                     \
    Bset[j_][0] = *(const short8*)(bP + (size_t)j_ * 16 * CDIM + (t1) * 64);      \
    Bset[j_][1] = *(const short8*)(bP + (size_t)j_ * 16 * CDIM + (t1) * 64 + 32); \
  }

#define MFMA_G(Aset, Bset, ks, j0)                                       \
  __builtin_amdgcn_s_setprio(1);                                         \
  _Pragma("unroll") for (int i_ = 0; i_ < 4; ++i_)                       \
  _Pragma("unroll") for (int j_ = 0; j_ < 2; ++j_)                       \
    acc[i_][j_ + j0] = __builtin_amdgcn_mfma_f32_16x16x32_bf16(          \
        Aset[i_], Bset[j_ + j0][ks], acc[i_][j_ + j0], 0, 0, 0);         \
  __builtin_amdgcn_s_setprio(0);

  // BODY(t): g0(ks0 j01) | issue B(t+1) | g1(ks0 j23) | read Ap(ks1) |
  // g2(ks1 j01) | vmcnt(8)+barrier | SA(t+2) + read Af(t+1) | g3(ks1 j23)
#define BODY(Bc, Bn, t)                                                  \
  {                                                                      \
    MFMA_G(Af, Bc, 0, 0);                                                \
    SB();                                                                \
    if ((t) + 1 < NKT) { ISSUE_B(Bn, (t) + 1); }                         \
    SB();                                                                \
    MFMA_G(Af, Bc, 0, 2);                                                \
    SB();                                                                \
    LDA4(Ap, oc + wm * 4096 + offs1);                                    \
    SB();                                                                \
    MFMA_G(Ap, Bc, 1, 0);                                                \
    SB();                                                                \
    if ((t) < NKT - 1) {                                                 \
      asm volatile("s_waitcnt vmcnt(8)" ::: "memory");                   \
      SB();                                                              \
      __builtin_amdgcn_s_barrier();                                      \
      SB();                                                              \
      if ((t) + 2 < NKT) SA_(os, (t) + 2);                               \
      LDA4(Af, on + wm * 4096 + offs0);                                  \
    }                                                                    \
    SB();                                                                \
    MFMA_G(Ap, Bc, 1, 2);                                                \
    SB();                                                                \
    int tmp_ = oc; oc = on; on = os; os = tmp_;                          \
  }

  // ---- prologue: stage A tiles 0,1; issue B(0); read A(0) ks0 frags ----
  SA_(0, 0); SA_(8192, 1);
  ISSUE_B(Bx, 0);
  asm volatile("s_waitcnt vmcnt(10)" ::: "memory");   // retire SA(0)
  SB();
  __builtin_amdgcn_s_barrier();
  SB();
  LDA4(Af, 0 + wm * 4096 + offs0);
  SB();

  int oc = 0, on = 8192, os = 16384;
  for (int t = 0; t < NKT; t += 2) {
    BODY(Bx, By, t);
    BODY(By, Bx, t + 1);
  }

  // epilogue: BN (folded) + ReLU, bf16 store.
  // C/D layout: col = lane&15, row = (lane>>4)*4 + reg  [m89 verified]
  const float* gh = gp + h * CDIM;
  const float* bh = bp + h * CDIM;
  const float* mh = mp + h * CDIM;
  const float* vh = vp + h * CDIM;
  const int colBase = nt * 256 + wn * 64 + fr;
  const int rowBase = mt * 128 + wm * 64 + fg * 4;
#pragma unroll
  for (int j = 0; j < 4; ++j) {
    const int col = colBase + j * 16;
    const float sc = gh[col] / sqrtf(vh[col] + BN_EPS);
    const float sh = bh[col] - mh[col] * sc;
#pragma unroll
    for (int i = 0; i < 4; ++i) {
      const int row = rowBase + i * 16;
#pragma unroll
      for (int rr = 0; rr < 4; ++rr) {
        float val = acc[i][j][rr] * sc + sh;
        val = val > 0.f ? val : 0.f;
        out[((size_t)h * MROWS + row + rr) * CDIM + col] = __float2bfloat16(val);
      }
    }
  }
}

// ---------------------------------------------------------------------------
// Pack final-layer weights into bf16 Wfb[3][16][2048], zero-padded.
// ---------------------------------------------------------------------------
__global__ __launch_bounds__(256) void pack_wf(
    const float* __restrict__ Wf0, const float* __restrict__ Wf1,
    const float* __restrict__ Wf2, __hip_bfloat16* __restrict__ Wfb) {
  int idx = blockIdx.x * 256 + threadIdx.x;   // 3*16*2048 = 98304
  if (idx >= 3 * 16 * CDIM) return;
  int h = idx / (16 * CDIM);
  int rem = idx - h * 16 * CDIM;
  int j = rem / CDIM;
  int k = rem - j * CDIM;
  float v = 0.f;
  if (h == 0)            v = Wf0[j * CDIM + k];
  else if (h == 1)       { if (j < 5) v = Wf1[j * CDIM + k]; }
  else                   { if (j < 5) v = Wf2[j * CDIM + k]; }
  Wfb[idx] = __float2bfloat16(v);
}

// ---------------------------------------------------------------------------
// Final 1x1 convs via MFMA, K-split 8 ways across waves.
// ---------------------------------------------------------------------------
__global__ __launch_bounds__(512) void final_mfma(
    const __hip_bfloat16* __restrict__ act,   // [3][4096][2048]
    const __hip_bfloat16* __restrict__ Wfb,   // [3][16][2048]
    const float* __restrict__ bf0, const float* __restrict__ bf1,
    const float* __restrict__ bf2, float* __restrict__ out)  // [4096][26]
{
  __shared__ float red[8][3][256];
  const int tid  = threadIdx.x;
  const int w    = tid >> 6;
  const int lane = tid & 63;
  const int r0   = blockIdx.x * 16;
  const int fr   = lane & 15;
  const int fk   = (lane >> 4) * 8;
  const int kbase = w * 256 + fk;

  f32x4 acc[3] = {};
  const __hip_bfloat16* aRow = act + (size_t)(r0 + fr) * CDIM + kbase;
  const __hip_bfloat16* bRow = Wfb + (size_t)fr * CDIM + kbase;
#pragma unroll
  for (int ks = 0; ks < 8; ++ks) {
    const int k = ks * 32;
#pragma unroll
    for (int h = 0; h < 3; ++h) {
      short8 a = *(const short8*)(aRow + (size_t)h * MROWS * CDIM + k);
      short8 b = *(const short8*)(bRow + h * 16 * CDIM + k);
      acc[h] = __builtin_amdgcn_mfma_f32_16x16x32_bf16(a, b, acc[h], 0, 0, 0);
    }
  }

  const int rb = (lane >> 4) * 4;
#pragma unroll
  for (int h = 0; h < 3; ++h)
#pragma unroll
    for (int r = 0; r < 4; ++r)
      red[w][h][(rb + r) * 16 + fr] = acc[h][r];
  __syncthreads();

  for (int e = tid; e < 768; e += 512) {
    const int h = e >> 8, idx = e & 255;
    const int row = idx >> 4, col = idx & 15;
    float s = 0.f;
#pragma unroll
    for (int w2 = 0; w2 < 8; ++w2) s += red[w2][h][idx];
    float* orow = out + (size_t)(r0 + row) * 26;
    if (h == 0)                 orow[col]      = s + bf0[col];
    else if (h == 1) { if (col < 5) orow[16 + col] = s + bf1[col]; }
    else             { if (col < 5) orow[21 + col] = s + bf2[col]; }
  }
}

// ---------------------------------------------------------------------------
extern "C" void kernel_launch(void* const* d_in, const int* in_sizes, int n_in,
                              void* d_out, int out_size, void* d_ws, size_t ws_size,
                              hipStream_t stream) {
  const float* feat = (const float*)d_in[0];
  const float* W1 = (const float*)d_in[1];
  const float* g1 = (const float*)d_in[2];
  const float* b1 = (const float*)d_in[3];
  const float* m1 = (const float*)d_in[4];
  const float* v1 = (const float*)d_in[5];
  const float* W2 = (const float*)d_in[6];
  const float* g2 = (const float*)d_in[7];
  const float* b2 = (const float*)d_in[8];
  const float* m2 = (const float*)d_in[9];
  const float* v2 = (const float*)d_in[10];
  const float* W3 = (const float*)d_in[11];
  const float* g3 = (const float*)d_in[12];
  const float* b3 = (const float*)d_in[13];
  const float* m3 = (const float*)d_in[14];
  const float* v3 = (const float*)d_in[15];
  const float* Wf0 = (const float*)d_in[16];
  const float* bf0 = (const float*)d_in[17];
  const float* Wf1 = (const float*)d_in[18];
  const float* bf1 = (const float*)d_in[19];
  const float* Wf2 = (const float*)d_in[20];
  const float* bf2 = (const float*)d_in[21];
  float* out = (float*)d_out;

  // workspace: wbuf 24MB | actA 48MB | actB 48MB (features bf16 overlaps actB)
  // Wfb (192KB) reuses wbuf after gemm3 has consumed W3.
  char* ws = (char*)d_ws;
  __hip_bfloat16* wbuf = (__hip_bfloat16*)ws;
  __hip_bfloat16* actA = (__hip_bfloat16*)(ws + 25165824);
  __hip_bfloat16* actB = (__hip_bfloat16*)(ws + 25165824 + 50331648);
  __hip_bfloat16* xb   = actB;
  __hip_bfloat16* Wfb  = wbuf;

  const int nW4 = (3 * CDIM * CDIM) / 4;
  const int nX4 = (MROWS * CDIM) / 4;
  const long long hstride = (long long)MROWS * CDIM;

  cvt_f32_bf16<<<2048, 256, 0, stream>>>(feat, (unsigned short*)xb, nX4);

  cvt_f32_bf16<<<2048, 256, 0, stream>>>(W1, (unsigned short*)wbuf, nW4);
  gemm_bdir<<<768, 512, 0, stream>>>(xb, 0LL, wbuf, g1, b1, m1, v1, actA);

  cvt_f32_bf16<<<2048, 256, 0, stream>>>(W2, (unsigned short*)wbuf, nW4);
  gemm_bdir<<<768, 512, 0, stream>>>(actA, hstride, wbuf, g2, b2, m2, v2, actB);

  cvt_f32_bf16<<<2048, 256, 0, stream>>>(W3, (unsigned short*)wbuf, nW4);
  gemm_bdir<<<768, 512, 0, stream>>>(actB, hstride, wbuf, g3, b3, m3, v3, actA);

  pack_wf<<<384, 256, 0, stream>>>(Wf0, Wf1, Wf2, Wfb);
  final_mfma<<<256, 512, 0, stream>>>(actA, Wfb, bf0, bf1, bf2, out);
}

// Round 9
// 451.121 us; speedup vs baseline: 1.5633x; 1.5633x over previous
//
#include <hip/hip_runtime.h>
#include <hip/hip_bf16.h>

typedef __attribute__((ext_vector_type(8))) short short8;
typedef __attribute__((ext_vector_type(4))) float f32x4;

#define BN_EPS 1e-5f
#define MROWS 4096
#define CDIM 2048
#define NKT 32   // K tiles of 64

#define SB() __builtin_amdgcn_sched_barrier(0)

__device__ __forceinline__ void gload_lds16(const void* g, void* l) {
  __builtin_amdgcn_global_load_lds(
      (const __attribute__((address_space(1))) void*)g,
      (__attribute__((address_space(3))) void*)l, 16, 0, 0);
}

__device__ __forceinline__ short bf16b(float x) {
  __hip_bfloat16 h = __float2bfloat16(x);
  return *(short*)&h;
}
__device__ __forceinline__ short8 cvt8(float4 a, float4 b) {
  short8 r;
  r[0] = bf16b(a.x); r[1] = bf16b(a.y); r[2] = bf16b(a.z); r[3] = bf16b(a.w);
  r[4] = bf16b(b.x); r[5] = bf16b(b.y); r[6] = bf16b(b.z); r[7] = bf16b(b.w);
  return r;
}

// ---------------------------------------------------------------------------
// fp32 -> bf16 conversion (vectorized float4 -> ushort4) — features only now.
// ---------------------------------------------------------------------------
__global__ __launch_bounds__(256) void cvt_f32_bf16(const float* __restrict__ in,
                                                    unsigned short* __restrict__ out,
                                                    int n4) {
  int idx = blockIdx.x * blockDim.x + threadIdx.x;
  int stride = gridDim.x * blockDim.x;
  for (int i = idx; i < n4; i += stride) {
    float4 vv = ((const float4*)in)[i];
    ushort4 o;
    o.x = (unsigned short)bf16b(vv.x);
    o.y = (unsigned short)bf16b(vv.y);
    o.z = (unsigned short)bf16b(vv.z);
    o.w = (unsigned short)bf16b(vv.w);
    ((ushort4*)out)[i] = o;
  }
}

// ---------------------------------------------------------------------------
// 128x256 tile, BK=64, 3-deep LDS ring (144 KiB, 1 block/CU), grid 768 = 3
// exact rounds. 8 waves (2M x 4N) of 64x64, acc[4][4]. R6 schedule.
// R9: W read as fp32 directly — B staged via regs (8 dwordx4 issued 2 tiles
// ahead, double-buffered) + cvt + 4 linear conflict-free ds_write_b128 at
// tile start (phase W). A stays on global_load_lds. LDS layout & fragment
// reads identical to R6 (swizzle chunk^=(row&7), 0 conflicts).
// vmcnt ledger: phase W vmcnt(2) retires Breg(t+1) (newer: SA(t+1)x2);
// sync vmcnt(10) retires SA(t+1) (newer: B32(t+2)x8 + SA(t+2)x2), plus
// lgkmcnt(0) to drain phase-W ds_writes before the barrier.
// out[h][m][d] = relu((sum_c A[h][m][c]*W[h][d][c])*scale + shift)
// ---------------------------------------------------------------------------
__global__ __launch_bounds__(512, 2) void gemm_fw(
    const __hip_bfloat16* __restrict__ A, long long a_hstride,
    const float* __restrict__ W32,
    const float* __restrict__ gp, const float* __restrict__ bp,
    const float* __restrict__ mp, const float* __restrict__ vp,
    __hip_bfloat16* __restrict__ out)
{
  __shared__ __hip_bfloat16 sm[73728];   // 144 KiB = 3 slots x 24576 elems

  const int tid  = threadIdx.x;
  const int w    = tid >> 6;
  const int lane = tid & 63;

  // XCD-bijective swizzle over 768 blocks (768 % 8 == 0, q = 96)
  const int bid = blockIdx.x;
  const int swz = (bid & 7) * 96 + (bid >> 3);
  const int h   = swz >> 8;          // 256 tiles per head
  const int rem = swz & 255;
  const int mt  = rem >> 3;          // 32 m-tiles of 128
  const int nt  = rem & 7;           // 8 n-tiles of 256

  const __hip_bfloat16* Abase = A + (size_t)h * (size_t)a_hstride + (size_t)(mt * 128) * CDIM;

  // A staging: tile 128x64 = 1024 16B slots; thread t -> slots t, t+512.
  // slot s: row=s>>3, chunk=s&7, global chunk = chunk ^ (row&7).
  const int row0 = tid >> 3;
  const int ch0  = (tid & 7) ^ (row0 & 7);
  const __hip_bfloat16* aSrc = Abase + (size_t)row0 * CDIM + ch0 * 8;
  // B source (fp32): rows nt*256 + row0 + {0,64,128,192}, cols ch0*8 (+t*64)
  const float* bP32 = W32 + ((size_t)h * CDIM + (size_t)(nt * 256 + row0)) * CDIM + ch0 * 8;

  // fragment read offsets (swizzled)
  const int wm = w >> 2, wn = w & 3;
  const int fr = lane & 15, fg = lane >> 4;
  const int offs0 = fr * 64 + ((fg ^ (fr & 7)) << 3);        // ksub 0
  const int offs1 = fr * 64 + (((fg + 4) ^ (fr & 7)) << 3);  // ksub 1
  const int aoffs0 = wm * 4096 + offs0;
  const int aoffs1 = wm * 4096 + offs1;
  const int boffs0 = 8192 + wn * 4096 + offs0;
  const int boffs1 = 8192 + wn * 4096 + offs1;

  auto SA_ = [&](int buf, int t) {
    __hip_bfloat16* dp = &sm[buf + tid * 8];
    gload_lds16(aSrc + t * 64, dp);
    gload_lds16(aSrc + (size_t)64 * CDIM + t * 64, dp + 4096);
  };

  f32x4 acc[4][4] = {};
  short8 Af[4], Ap[4], B0[2], B1[2], B0p[2], B1p[2];
  float4 bgA[8], bgB[8];   // double-buffered fp32 B staging regs

#define ISSUE_B32(dst, t2)                                               \
  _Pragma("unroll") for (int q_ = 0; q_ < 4; ++q_) {                     \
    dst[q_ * 2]     = *(const float4*)(bP32 + (size_t)q_ * 64 * CDIM + (t2) * 64);     \
    dst[q_ * 2 + 1] = *(const float4*)(bP32 + (size_t)q_ * 64 * CDIM + (t2) * 64 + 4); \
  }

#define CVT_WRITE(src, slotOff)                                          \
  _Pragma("unroll") for (int q_ = 0; q_ < 4; ++q_) {                     \
    short8 v_ = cvt8(src[q_ * 2], src[q_ * 2 + 1]);                      \
    *(short8*)&sm[(slotOff) + 8192 + q_ * 4096 + tid * 8] = v_;          \
  }

#define LDA4(dst, base)                                                  \
  _Pragma("unroll") for (int i_ = 0; i_ < 4; ++i_)                       \
    dst[i_] = *(const short8*)&sm[(base) + i_ * 1024];
#define LDB2(dst, base, j0)                                              \
  _Pragma("unroll") for (int j_ = 0; j_ < 2; ++j_)                       \
    dst[j_] = *(const short8*)&sm[(base) + ((j0) + j_) * 1024];

#define MFMA_G(joff, Aset, Bset)                                         \
  __builtin_amdgcn_s_setprio(1);                                         \
  _Pragma("unroll") for (int i_ = 0; i_ < 4; ++i_)                       \
  _Pragma("unroll") for (int j_ = 0; j_ < 2; ++j_)                       \
    acc[i_][j_ + joff] = __builtin_amdgcn_mfma_f32_16x16x32_bf16(        \
        Aset[i_], Bset[j_], acc[i_][j_ + joff], 0, 0, 0);                \
  __builtin_amdgcn_s_setprio(0);

  // BODY(t): phaseW (cvt+write B(t+1) -> on) | g0..g2 as R6 | g1 issues
  // B32(t+2)+SA(t+2) | sync vmcnt(10)+lgkm0+barrier | pre-reads(on) | g3
#define BODY(BW, BI, t)                                                  \
  {                                                                      \
    if ((t) + 1 < NKT) {                                                 \
      asm volatile("s_waitcnt vmcnt(2)" ::: "memory");                   \
      SB();                                                              \
      CVT_WRITE(BW, on);                                                 \
    }                                                                    \
    SB();                                                                \
    MFMA_G(0, Af, B0); SB();                                             \
    LDB2(B0p, oc + boffs1, 0); SB();                                     \
    MFMA_G(2, Af, B1); SB();                                             \
    LDA4(Ap, oc + aoffs1);                                               \
    if ((t) + 2 < NKT) { ISSUE_B32(BI, (t) + 2); SA_(os, (t) + 2); }     \
    SB();                                                                \
    MFMA_G(0, Ap, B0p); SB();                                            \
    LDB2(B1p, oc + boffs1, 2); SB();                                     \
    if ((t) < NKT - 1) {                                                 \
      if ((t) + 2 < NKT) { asm volatile("s_waitcnt vmcnt(10) lgkmcnt(0)" ::: "memory"); } \
      else               { asm volatile("s_waitcnt vmcnt(0) lgkmcnt(0)" ::: "memory"); }  \
      SB();                                                              \
      __builtin_amdgcn_s_barrier();                                      \
      SB();                                                              \
      LDA4(Af, on + aoffs0);                                             \
      LDB2(B0, on + boffs0, 0);                                          \
      LDB2(B1, on + boffs0, 2);                                          \
    }                                                                    \
    SB();                                                                \
    MFMA_G(2, Ap, B1p); SB();                                            \
    int tmp_ = oc; oc = on; on = os; os = tmp_;                          \
  }

  // ---- prologue: SA(0), B32(0)->bgA, B32(1)->bgB, SA(1);
  //      retire B32(0) (vmcnt(10): newer = B32(1)x8 + SA(1)x2);
  //      cvt+write B(0) -> slot0; drain; barrier; pre-read tile0 frags. ----
  SA_(0, 0);
  ISSUE_B32(bgA, 0);
  ISSUE_B32(bgB, 1);
  SA_(24576, 1);
  asm volatile("s_waitcnt vmcnt(10)" ::: "memory");
  SB();
  CVT_WRITE(bgA, 0);
  asm volatile("s_waitcnt lgkmcnt(0)" ::: "memory");
  SB();
  __builtin_amdgcn_s_barrier();
  SB();
  LDA4(Af, 0 + aoffs0);
  LDB2(B0, 0 + boffs0, 0);
  LDB2(B1, 0 + boffs0, 2);
  SB();

  int oc = 0, on = 24576, os = 49152;
  for (int t = 0; t < NKT; t += 2) {
    BODY(bgB, bgA, t);      // consume B(t+1)=bgB, issue B(t+2)->bgA
    BODY(bgA, bgB, t + 1);  // consume B(t+2)=bgA, issue B(t+3)->bgB
  }

  // epilogue: BN (folded) + ReLU, bf16 store.
  // C/D layout: col = lane&15, row = (lane>>4)*4 + reg  [m89 verified]
  const float* gh = gp + h * CDIM;
  const float* bh = bp + h * CDIM;
  const float* mh = mp + h * CDIM;
  const float* vh = vp + h * CDIM;
  const int colBase = nt * 256 + wn * 64 + fr;
  const int rowBase = mt * 128 + wm * 64 + fg * 4;
#pragma unroll
  for (int j = 0; j < 4; ++j) {
    const int col = colBase + j * 16;
    const float sc = gh[col] / sqrtf(vh[col] + BN_EPS);
    const float sh = bh[col] - mh[col] * sc;
#pragma unroll
    for (int i = 0; i < 4; ++i) {
      const int row = rowBase + i * 16;
#pragma unroll
      for (int rr = 0; rr < 4; ++rr) {
        float val = acc[i][j][rr] * sc + sh;
        val = val > 0.f ? val : 0.f;
        out[((size_t)h * MROWS + row + rr) * CDIM + col] = __float2bfloat16(val);
      }
    }
  }
}

// ---------------------------------------------------------------------------
// Pack final-layer weights into bf16 Wfb[3][16][2048], zero-padded.
// ---------------------------------------------------------------------------
__global__ __launch_bounds__(256) void pack_wf(
    const float* __restrict__ Wf0, const float* __restrict__ Wf1,
    const float* __restrict__ Wf2, __hip_bfloat16* __restrict__ Wfb) {
  int idx = blockIdx.x * 256 + threadIdx.x;   // 3*16*2048 = 98304
  if (idx >= 3 * 16 * CDIM) return;
  int h = idx / (16 * CDIM);
  int rem = idx - h * 16 * CDIM;
  int j = rem / CDIM;
  int k = rem - j * CDIM;
  float v = 0.f;
  if (h == 0)            v = Wf0[j * CDIM + k];
  else if (h == 1)       { if (j < 5) v = Wf1[j * CDIM + k]; }
  else                   { if (j < 5) v = Wf2[j * CDIM + k]; }
  Wfb[idx] = __float2bfloat16(v);
}

// ---------------------------------------------------------------------------
// Final 1x1 convs via MFMA, K-split 8 ways across waves.
// ---------------------------------------------------------------------------
__global__ __launch_bounds__(512) void final_mfma(
    const __hip_bfloat16* __restrict__ act,   // [3][4096][2048]
    const __hip_bfloat16* __restrict__ Wfb,   // [3][16][2048]
    const float* __restrict__ bf0, const float* __restrict__ bf1,
    const float* __restrict__ bf2, float* __restrict__ out)  // [4096][26]
{
  __shared__ float red[8][3][256];
  const int tid  = threadIdx.x;
  const int w    = tid >> 6;
  const int lane = tid & 63;
  const int r0   = blockIdx.x * 16;
  const int fr   = lane & 15;
  const int fk   = (lane >> 4) * 8;
  const int kbase = w * 256 + fk;

  f32x4 acc[3] = {};
  const __hip_bfloat16* aRow = act + (size_t)(r0 + fr) * CDIM + kbase;
  const __hip_bfloat16* bRow = Wfb + (size_t)fr * CDIM + kbase;
#pragma unroll
  for (int ks = 0; ks < 8; ++ks) {
    const int k = ks * 32;
#pragma unroll
    for (int h = 0; h < 3; ++h) {
      short8 a = *(const short8*)(aRow + (size_t)h * MROWS * CDIM + k);
      short8 b = *(const short8*)(bRow + h * 16 * CDIM + k);
      acc[h] = __builtin_amdgcn_mfma_f32_16x16x32_bf16(a, b, acc[h], 0, 0, 0);
    }
  }

  const int rb = (lane >> 4) * 4;
#pragma unroll
  for (int h = 0; h < 3; ++h)
#pragma unroll
    for (int r = 0; r < 4; ++r)
      red[w][h][(rb + r) * 16 + fr] = acc[h][r];
  __syncthreads();

  for (int e = tid; e < 768; e += 512) {
    const int h = e >> 8, idx = e & 255;
    const int row = idx >> 4, col = idx & 15;
    float s = 0.f;
#pragma unroll
    for (int w2 = 0; w2 < 8; ++w2) s += red[w2][h][idx];
    float* orow = out + (size_t)(r0 + row) * 26;
    if (h == 0)                 orow[col]      = s + bf0[col];
    else if (h == 1) { if (col < 5) orow[16 + col] = s + bf1[col]; }
    else             { if (col < 5) orow[21 + col] = s + bf2[col]; }
  }
}

// ---------------------------------------------------------------------------
extern "C" void kernel_launch(void* const* d_in, const int* in_sizes, int n_in,
                              void* d_out, int out_size, void* d_ws, size_t ws_size,
                              hipStream_t stream) {
  const float* feat = (const float*)d_in[0];
  const float* W1 = (const float*)d_in[1];
  const float* g1 = (const float*)d_in[2];
  const float* b1 = (const float*)d_in[3];
  const float* m1 = (const float*)d_in[4];
  const float* v1 = (const float*)d_in[5];
  const float* W2 = (const float*)d_in[6];
  const float* g2 = (const float*)d_in[7];
  const float* b2 = (const float*)d_in[8];
  const float* m2 = (const float*)d_in[9];
  const float* v2 = (const float*)d_in[10];
  const float* W3 = (const float*)d_in[11];
  const float* g3 = (const float*)d_in[12];
  const float* b3 = (const float*)d_in[13];
  const float* m3 = (const float*)d_in[14];
  const float* v3 = (const float*)d_in[15];
  const float* Wf0 = (const float*)d_in[16];
  const float* bf0 = (const float*)d_in[17];
  const float* Wf1 = (const float*)d_in[18];
  const float* bf1 = (const float*)d_in[19];
  const float* Wf2 = (const float*)d_in[20];
  const float* bf2 = (const float*)d_in[21];
  float* out = (float*)d_out;

  // workspace: Wfb 192KB | actA 48MB | actB 48MB (features bf16 = actB start)
  char* ws = (char*)d_ws;
  __hip_bfloat16* Wfb  = (__hip_bfloat16*)ws;
  __hip_bfloat16* actA = (__hip_bfloat16*)(ws + 262144);
  __hip_bfloat16* actB = (__hip_bfloat16*)(ws + 262144 + 50331648);
  __hip_bfloat16* xb   = actB;

  const int nX4 = (MROWS * CDIM) / 4;
  const long long hstride = (long long)MROWS * CDIM;

  cvt_f32_bf16<<<2048, 256, 0, stream>>>(feat, (unsigned short*)xb, nX4);

  gemm_fw<<<768, 512, 0, stream>>>(xb, 0LL, W1, g1, b1, m1, v1, actA);
  gemm_fw<<<768, 512, 0, stream>>>(actA, hstride, W2, g2, b2, m2, v2, actB);
  gemm_fw<<<768, 512, 0, stream>>>(actB, hstride, W3, g3, b3, m3, v3, actA);

  pack_wf<<<384, 256, 0, stream>>>(Wf0, Wf1, Wf2, Wfb);
  final_mfma<<<256, 512, 0, stream>>>(actA, Wfb, bf0, bf1, bf2, out);
}

// Round 10
// 360.015 us; speedup vs baseline: 1.9589x; 1.2531x over previous
//
#include <hip/hip_runtime.h>
#include <hip/hip_bf16.h>

typedef __attribute__((ext_vector_type(8))) short short8;
typedef __attribute__((ext_vector_type(4))) float f32x4;

#define BN_EPS 1e-5f
#define MROWS 4096
#define CDIM 2048
#define NKT 32   // K tiles of 64

#define SB() __builtin_amdgcn_sched_barrier(0)

__device__ __forceinline__ void gload_lds16(const void* g, void* l) {
  __builtin_amdgcn_global_load_lds(
      (const __attribute__((address_space(1))) void*)g,
      (__attribute__((address_space(3))) void*)l, 16, 0, 0);
}

__device__ __forceinline__ unsigned short bf16u(float x) {
  __hip_bfloat16 h = __float2bfloat16(x);
  return *(unsigned short*)&h;
}

// ---------------------------------------------------------------------------
// fp32 -> bf16 conversion (vectorized float4 -> ushort4)
// ---------------------------------------------------------------------------
__global__ __launch_bounds__(256) void cvt_f32_bf16(const float* __restrict__ in,
                                                    unsigned short* __restrict__ out,
                                                    int n4) {
  int idx = blockIdx.x * blockDim.x + threadIdx.x;
  int stride = gridDim.x * blockDim.x;
  for (int i = idx; i < n4; i += stride) {
    float4 vv = ((const float4*)in)[i];
    ushort4 o;
    o.x = bf16u(vv.x); o.y = bf16u(vv.y); o.z = bf16u(vv.z); o.w = bf16u(vv.w);
    ((ushort4*)out)[i] = o;
  }
}

// Two-tensor variant: converts feat and W1 in a single launch.
__global__ __launch_bounds__(256) void cvt2_f32_bf16(
    const float* __restrict__ inA, unsigned short* __restrict__ outA, int nA4,
    const float* __restrict__ inB, unsigned short* __restrict__ outB, int nB4) {
  int idx = blockIdx.x * blockDim.x + threadIdx.x;
  int stride = gridDim.x * blockDim.x;
  int tot = nA4 + nB4;
  for (int i = idx; i < tot; i += stride) {
    const float4* src; ushort4* dst; int k;
    if (i < nA4) { src = (const float4*)inA; dst = (ushort4*)outA; k = i; }
    else         { src = (const float4*)inB; dst = (ushort4*)outB; k = i - nA4; }
    float4 vv = src[k];
    ushort4 o;
    o.x = bf16u(vv.x); o.y = bf16u(vv.y); o.z = bf16u(vv.z); o.w = bf16u(vv.w);
    dst[k] = o;
  }
}

// ---------------------------------------------------------------------------
// 128x256 tile, BK=64, 3-deep LDS ring (144 KiB, 1 block/CU), grid 768 = 3
// exact rounds. 8 waves (2M x 4N) of 64x64, acc[4][4]. R7 schedule:
// tile t+1's ks0 fragment reads issue UNDER tile t's last MFMA group; one
// {vmcnt lgkmcnt(0)} + barrier per K-tile (mid-tile).
// R10: epilogue bounces the C tile through the dead ring LDS (pad-264 rows)
// and stores fully-coalesced b128 rows -> WRITE_SIZE 49MB -> ~16MB.
// Swizzle chunk^=(row&7) on 16B chunks (R3/R6-verified, 0 conflicts).
// out[h][m][d] = relu((sum_c A[h][m][c]*W[h][d][c])*scale + shift)
// ---------------------------------------------------------------------------
__global__ __launch_bounds__(512, 2) void gemm128_ring(
    const __hip_bfloat16* __restrict__ A, long long a_hstride,
    const __hip_bfloat16* __restrict__ W,
    const float* __restrict__ gp, const float* __restrict__ bp,
    const float* __restrict__ mp, const float* __restrict__ vp,
    __hip_bfloat16* __restrict__ out)
{
  __shared__ __hip_bfloat16 sm[73728];   // 144 KiB = 3 x 24576 elems

  const int tid  = threadIdx.x;
  const int w    = tid >> 6;
  const int lane = tid & 63;

  // XCD-bijective swizzle over 768 blocks (768 % 8 == 0, q = 96)
  const int bid = blockIdx.x;
  const int swz = (bid & 7) * 96 + (bid >> 3);
  const int h   = swz >> 8;          // 256 tiles per head
  const int rem = swz & 255;
  const int mt  = rem >> 3;          // 32 m-tiles of 128
  const int nt  = rem & 7;           // 8 n-tiles of 256

  const __hip_bfloat16* Abase = A + (size_t)h * (size_t)a_hstride + (size_t)(mt * 128) * CDIM;
  const __hip_bfloat16* Bbase = W + ((size_t)h * CDIM + (size_t)(nt * 256)) * CDIM;

  // staging: A tile 128x64 = 1024 16B slots (thread t: slots t, t+512);
  // B tile 256x64 = 2048 slots. slot s: row=s>>3, chunk=s&7,
  // global chunk = chunk ^ (row&7).
  const int row0 = tid >> 3;
  const int ch0  = (tid & 7) ^ (row0 & 7);
  const __hip_bfloat16* aSrc = Abase + (size_t)row0 * CDIM + ch0 * 8;
  const __hip_bfloat16* bSrc = Bbase + (size_t)row0 * CDIM + ch0 * 8;

  // fragment read offsets (swizzled)
  const int wm = w >> 2, wn = w & 3;
  const int fr = lane & 15, fg = lane >> 4;
  const int offs0 = fr * 64 + ((fg ^ (fr & 7)) << 3);        // ksub 0
  const int offs1 = fr * 64 + (((fg + 4) ^ (fr & 7)) << 3);  // ksub 1
  const int aoffs0 = wm * 4096 + offs0;
  const int aoffs1 = wm * 4096 + offs1;
  const int boffs0 = 8192 + wn * 4096 + offs0;
  const int boffs1 = 8192 + wn * 4096 + offs1;

  auto SA_ = [&](int buf, int t) {
    __hip_bfloat16* dp = &sm[buf + tid * 8];
    gload_lds16(aSrc + t * 64, dp);
    gload_lds16(aSrc + (size_t)64 * CDIM + t * 64, dp + 4096);
  };
  auto SB0 = [&](int buf, int t) {
    __hip_bfloat16* dp = &sm[buf + 8192 + tid * 8];
    gload_lds16(bSrc + t * 64, dp);
    gload_lds16(bSrc + (size_t)64 * CDIM + t * 64, dp + 4096);
  };
  auto SB1 = [&](int buf, int t) {
    __hip_bfloat16* dp = &sm[buf + 8192 + 8192 + tid * 8];
    gload_lds16(bSrc + (size_t)128 * CDIM + t * 64, dp);
    gload_lds16(bSrc + (size_t)192 * CDIM + t * 64, dp + 4096);
  };

  f32x4 acc[4][4] = {};
  short8 Af[4], Ap[4], B0[2], B1[2], B0p[2], B1p[2];

#define LDA4(dst, base)                                                  \
  _Pragma("unroll") for (int i_ = 0; i_ < 4; ++i_)                       \
    dst[i_] = *(const short8*)&sm[(base) + i_ * 1024];
#define LDB2(dst, base, j0)                                              \
  _Pragma("unroll") for (int j_ = 0; j_ < 2; ++j_)                       \
    dst[j_] = *(const short8*)&sm[(base) + ((j0) + j_) * 1024];

#define MFMA_G(joff, Aset, Bset)                                         \
  __builtin_amdgcn_s_setprio(1);                                         \
  _Pragma("unroll") for (int i_ = 0; i_ < 4; ++i_)                       \
  _Pragma("unroll") for (int j_ = 0; j_ < 2; ++j_)                       \
    acc[i_][j_ + joff] = __builtin_amdgcn_mfma_f32_16x16x32_bf16(        \
        Aset[i_], Bset[j_], acc[i_][j_ + joff], 0, 0, 0);                \
  __builtin_amdgcn_s_setprio(0);

  // ---- prologue: stage tiles 0,1 into ring slots 0,1; read t0 ks0 frags ----
  SA_(0, 0); SB0(0, 0); SB1(0, 0);
  SA_(24576, 1); SB0(24576, 1); SB1(24576, 1);
  asm volatile("s_waitcnt vmcnt(6)" ::: "memory");
  SB();
  __builtin_amdgcn_s_barrier();
  SB();
  LDA4(Af, 0 + aoffs0);
  LDB2(B0, 0 + boffs0, 0);
  LDB2(B1, 0 + boffs0, 2);
  SB();

  int oc = 0, on = 24576, os = 49152;
  for (int t = 0; t < NKT; ++t) {
    // g0: ks0 j01; refill B0p <- ks1(oc)
    MFMA_G(0, Af, B0); SB();
    LDB2(B0p, oc + boffs1, 0); SB();
    // g1: ks0 j23; refill Ap <- ks1(oc); stage A(t+2) -> os
    MFMA_G(2, Af, B1); SB();
    LDA4(Ap, oc + aoffs1);
    if (t + 2 < NKT) SA_(os, t + 2);
    SB();
    // g2: ks1 j01; refill B1p <- ks1(oc); stage B0(t+2) -> os
    MFMA_G(0, Ap, B0p); SB();
    LDB2(B1p, oc + boffs1, 2);
    if (t + 2 < NKT) SB0(os, t + 2);
    SB();
    // mid-tile sync: t+1's staging landed (4 newer stage-loads outstanding);
    // lgkmcnt(0) so B1p (consumed after barrier) completes before any rewrite.
    if (t + 1 < NKT) {
      if (t + 2 < NKT) { asm volatile("s_waitcnt vmcnt(4) lgkmcnt(0)" ::: "memory"); }
      else             { asm volatile("s_waitcnt vmcnt(0) lgkmcnt(0)" ::: "memory"); }
      SB();
      __builtin_amdgcn_s_barrier();
      SB();
    }
    // g3: ks1 j23; stage B1(t+2) -> os; read t+1 ks0 frags (on) under MFMA
    MFMA_G(2, Ap, B1p); SB();
    if (t + 2 < NKT) SB1(os, t + 2);
    if (t + 1 < NKT) {
      LDA4(Af, on + aoffs0);
      LDB2(B0, on + boffs0, 0);
      LDB2(B1, on + boffs0, 2);
    }
    SB();
    const int tmp = oc; oc = on; on = os; os = tmp;
  }

  // ---- epilogue: BN (folded) + ReLU; LDS bounce for coalesced stores ----
  // C/D layout: col = lane&15, row = (lane>>4)*4 + reg  [m89 verified]
  __syncthreads();   // ring dead, all waves' MFMA reads complete
  {
    const float* gh = gp + h * CDIM;
    const float* bh = bp + h * CDIM;
    const float* mh = mp + h * CDIM;
    const float* vh = vp + h * CDIM;
    const int colL = wn * 64 + fr;       // 0..255 within tile
    const int rowL = wm * 64 + fg * 4;   // 0..127 within tile
#pragma unroll
    for (int j = 0; j < 4; ++j) {
      const int col = nt * 256 + colL + j * 16;
      const float sc = gh[col] / sqrtf(vh[col] + BN_EPS);
      const float sh = bh[col] - mh[col] * sc;
#pragma unroll
      for (int i = 0; i < 4; ++i) {
#pragma unroll
        for (int rr = 0; rr < 4; ++rr) {
          float val = acc[i][j][rr] * sc + sh;
          val = val > 0.f ? val : 0.f;
          // pad-264 row stride spreads fg-groups across banks
          sm[(rowL + i * 16 + rr) * 264 + colL + j * 16] = __float2bfloat16(val);
        }
      }
    }
    __syncthreads();
    // coalesced copy: 128 rows x 256 cols bf16, 8 passes of b128/thread
    __hip_bfloat16* obase = out + ((size_t)h * MROWS + (size_t)mt * 128) * CDIM + nt * 256;
#pragma unroll
    for (int p = 0; p < 8; ++p) {
      const int flat = p * 4096 + tid * 8;   // elem index in 128x256
      const int row  = flat >> 8;
      const int colb = flat & 255;
      short8 v = *(const short8*)&sm[row * 264 + colb];
      *(short8*)&obase[(size_t)row * CDIM + colb] = v;
    }
  }
}

// ---------------------------------------------------------------------------
// Pack final-layer weights into bf16 Wfb[3][16][2048], zero-padded.
// ---------------------------------------------------------------------------
__global__ __launch_bounds__(256) void pack_wf(
    const float* __restrict__ Wf0, const float* __restrict__ Wf1,
    const float* __restrict__ Wf2, __hip_bfloat16* __restrict__ Wfb) {
  int idx = blockIdx.x * 256 + threadIdx.x;   // 3*16*2048 = 98304
  if (idx >= 3 * 16 * CDIM) return;
  int h = idx / (16 * CDIM);
  int rem = idx - h * 16 * CDIM;
  int j = rem / CDIM;
  int k = rem - j * CDIM;
  float v = 0.f;
  if (h == 0)            v = Wf0[j * CDIM + k];
  else if (h == 1)       { if (j < 5) v = Wf1[j * CDIM + k]; }
  else                   { if (j < 5) v = Wf2[j * CDIM + k]; }
  Wfb[idx] = __float2bfloat16(v);
}

// ---------------------------------------------------------------------------
// Final 1x1 convs via MFMA, K-split 8 ways across waves.
// ---------------------------------------------------------------------------
__global__ __launch_bounds__(512) void final_mfma(
    const __hip_bfloat16* __restrict__ act,   // [3][4096][2048]
    const __hip_bfloat16* __restrict__ Wfb,   // [3][16][2048]
    const float* __restrict__ bf0, const float* __restrict__ bf1,
    const float* __restrict__ bf2, float* __restrict__ out)  // [4096][26]
{
  __shared__ float red[8][3][256];
  const int tid  = threadIdx.x;
  const int w    = tid >> 6;
  const int lane = tid & 63;
  const int r0   = blockIdx.x * 16;
  const int fr   = lane & 15;
  const int fk   = (lane >> 4) * 8;
  const int kbase = w * 256 + fk;

  f32x4 acc[3] = {};
  const __hip_bfloat16* aRow = act + (size_t)(r0 + fr) * CDIM + kbase;
  const __hip_bfloat16* bRow = Wfb + (size_t)fr * CDIM + kbase;
#pragma unroll
  for (int ks = 0; ks < 8; ++ks) {
    const int k = ks * 32;
#pragma unroll
    for (int h = 0; h < 3; ++h) {
      short8 a = *(const short8*)(aRow + (size_t)h * MROWS * CDIM + k);
      short8 b = *(const short8*)(bRow + h * 16 * CDIM + k);
      acc[h] = __builtin_amdgcn_mfma_f32_16x16x32_bf16(a, b, acc[h], 0, 0, 0);
    }
  }

  const int rb = (lane >> 4) * 4;
#pragma unroll
  for (int h = 0; h < 3; ++h)
#pragma unroll
    for (int r = 0; r < 4; ++r)
      red[w][h][(rb + r) * 16 + fr] = acc[h][r];
  __syncthreads();

  for (int e = tid; e < 768; e += 512) {
    const int h = e >> 8, idx = e & 255;
    const int row = idx >> 4, col = idx & 15;
    float s = 0.f;
#pragma unroll
    for (int w2 = 0; w2 < 8; ++w2) s += red[w2][h][idx];
    float* orow = out + (size_t)(r0 + row) * 26;
    if (h == 0)                 orow[col]      = s + bf0[col];
    else if (h == 1) { if (col < 5) orow[16 + col] = s + bf1[col]; }
    else             { if (col < 5) orow[21 + col] = s + bf2[col]; }
  }
}

// ---------------------------------------------------------------------------
extern "C" void kernel_launch(void* const* d_in, const int* in_sizes, int n_in,
                              void* d_out, int out_size, void* d_ws, size_t ws_size,
                              hipStream_t stream) {
  const float* feat = (const float*)d_in[0];
  const float* W1 = (const float*)d_in[1];
  const float* g1 = (const float*)d_in[2];
  const float* b1 = (const float*)d_in[3];
  const float* m1 = (const float*)d_in[4];
  const float* v1 = (const float*)d_in[5];
  const float* W2 = (const float*)d_in[6];
  const float* g2 = (const float*)d_in[7];
  const float* b2 = (const float*)d_in[8];
  const float* m2 = (const float*)d_in[9];
  const float* v2 = (const float*)d_in[10];
  const float* W3 = (const float*)d_in[11];
  const float* g3 = (const float*)d_in[12];
  const float* b3 = (const float*)d_in[13];
  const float* m3 = (const float*)d_in[14];
  const float* v3 = (const float*)d_in[15];
  const float* Wf0 = (const float*)d_in[16];
  const float* bf0 = (const float*)d_in[17];
  const float* Wf1 = (const float*)d_in[18];
  const float* bf1 = (const float*)d_in[19];
  const float* Wf2 = (const float*)d_in[20];
  const float* bf2 = (const float*)d_in[21];
  float* out = (float*)d_out;

  // workspace: wbuf 24MB | actA 48MB | actB 48MB (features bf16 overlaps actB)
  // Wfb (192KB) reuses wbuf after gemm3 has consumed W3.
  char* ws = (char*)d_ws;
  __hip_bfloat16* wbuf = (__hip_bfloat16*)ws;
  __hip_bfloat16* actA = (__hip_bfloat16*)(ws + 25165824);
  __hip_bfloat16* actB = (__hip_bfloat16*)(ws + 25165824 + 50331648);
  __hip_bfloat16* xb   = actB;
  __hip_bfloat16* Wfb  = wbuf;

  const int nW4 = (3 * CDIM * CDIM) / 4;
  const int nX4 = (MROWS * CDIM) / 4;
  const long long hstride = (long long)MROWS * CDIM;

  cvt2_f32_bf16<<<2048, 256, 0, stream>>>(feat, (unsigned short*)xb, nX4,
                                          W1, (unsigned short*)wbuf, nW4);
  gemm128_ring<<<768, 512, 0, stream>>>(xb, 0LL, wbuf, g1, b1, m1, v1, actA);

  cvt_f32_bf16<<<2048, 256, 0, stream>>>(W2, (unsigned short*)wbuf, nW4);
  gemm128_ring<<<768, 512, 0, stream>>>(actA, hstride, wbuf, g2, b2, m2, v2, actB);

  cvt_f32_bf16<<<2048, 256, 0, stream>>>(W3, (unsigned short*)wbuf, nW4);
  gemm128_ring<<<768, 512, 0, stream>>>(actB, hstride, wbuf, g3, b3, m3, v3, actA);

  pack_wf<<<384, 256, 0, stream>>>(Wf0, Wf1, Wf2, Wfb);
  final_mfma<<<256, 512, 0, stream>>>(actA, Wfb, bf0, bf1, bf2, out);
}

// Round 11
// 355.117 us; speedup vs baseline: 1.9859x; 1.0138x over previous
//
#include <hip/hip_runtime.h>
#include <hip/hip_bf16.h>

typedef __attribute__((ext_vector_type(8))) short short8;
typedef __attribute__((ext_vector_type(4))) float f32x4;

#define BN_EPS 1e-5f
#define MROWS 4096
#define CDIM 2048
#define NKT 32   // K tiles of 64

#define SB() __builtin_amdgcn_sched_barrier(0)

__device__ __forceinline__ void gload_lds16(const void* g, void* l) {
  __builtin_amdgcn_global_load_lds(
      (const __attribute__((address_space(1))) void*)g,
      (__attribute__((address_space(3))) void*)l, 16, 0, 0);
}

__device__ __forceinline__ unsigned short bf16u(float x) {
  __hip_bfloat16 h = __float2bfloat16(x);
  return *(unsigned short*)&h;
}

// ---------------------------------------------------------------------------
// fp32 -> bf16 conversion (vectorized float4 -> ushort4)
// ---------------------------------------------------------------------------
__global__ __launch_bounds__(256) void cvt_f32_bf16(const float* __restrict__ in,
                                                    unsigned short* __restrict__ out,
                                                    int n4) {
  int idx = blockIdx.x * blockDim.x + threadIdx.x;
  int stride = gridDim.x * blockDim.x;
  for (int i = idx; i < n4; i += stride) {
    float4 vv = ((const float4*)in)[i];
    ushort4 o;
    o.x = bf16u(vv.x); o.y = bf16u(vv.y); o.z = bf16u(vv.z); o.w = bf16u(vv.w);
    ((ushort4*)out)[i] = o;
  }
}

// Two-tensor variant: converts feat and W1 in a single launch.
__global__ __launch_bounds__(256) void cvt2_f32_bf16(
    const float* __restrict__ inA, unsigned short* __restrict__ outA, int nA4,
    const float* __restrict__ inB, unsigned short* __restrict__ outB, int nB4) {
  int idx = blockIdx.x * blockDim.x + threadIdx.x;
  int stride = gridDim.x * blockDim.x;
  int tot = nA4 + nB4;
  for (int i = idx; i < tot; i += stride) {
    const float4* src; ushort4* dst; int k;
    if (i < nA4) { src = (const float4*)inA; dst = (ushort4*)outA; k = i; }
    else         { src = (const float4*)inB; dst = (ushort4*)outB; k = i - nA4; }
    float4 vv = src[k];
    ushort4 o;
    o.x = bf16u(vv.x); o.y = bf16u(vv.y); o.z = bf16u(vv.z); o.w = bf16u(vv.w);
    dst[k] = o;
  }
}

// ---------------------------------------------------------------------------
// 128x256 tile, BK=64, 3-deep LDS ring (144 KiB, 1 block/CU), grid 768 = 3
// exact rounds. 8 waves (2M x 4N) of 64x64, acc[4][4]. R7 schedule:
// tile t+1's ks0 fragment reads issue UNDER tile t's last MFMA group; one
// {vmcnt lgkmcnt(0)} + barrier per K-tile (mid-tile).
// Epilogue: direct scattered stores (R7) — measured write-ideal (48 MiB
// = exact output size; R10's LDS bounce changed nothing, reverted).
// Swizzle chunk^=(row&7) on 16B chunks (R3/R6-verified, 0 conflicts).
// out[h][m][d] = relu((sum_c A[h][m][c]*W[h][d][c])*scale + shift)
// ---------------------------------------------------------------------------
__global__ __launch_bounds__(512, 2) void gemm128_ring(
    const __hip_bfloat16* __restrict__ A, long long a_hstride,
    const __hip_bfloat16* __restrict__ W,
    const float* __restrict__ gp, const float* __restrict__ bp,
    const float* __restrict__ mp, const float* __restrict__ vp,
    __hip_bfloat16* __restrict__ out)
{
  __shared__ __hip_bfloat16 sm[73728];   // 144 KiB = 3 x 24576 elems

  const int tid  = threadIdx.x;
  const int w    = tid >> 6;
  const int lane = tid & 63;

  // XCD-bijective swizzle over 768 blocks (768 % 8 == 0, q = 96)
  const int bid = blockIdx.x;
  const int swz = (bid & 7) * 96 + (bid >> 3);
  const int h   = swz >> 8;          // 256 tiles per head
  const int rem = swz & 255;
  const int mt  = rem >> 3;          // 32 m-tiles of 128
  const int nt  = rem & 7;           // 8 n-tiles of 256

  const __hip_bfloat16* Abase = A + (size_t)h * (size_t)a_hstride + (size_t)(mt * 128) * CDIM;
  const __hip_bfloat16* Bbase = W + ((size_t)h * CDIM + (size_t)(nt * 256)) * CDIM;

  // staging: A tile 128x64 = 1024 16B slots (thread t: slots t, t+512);
  // B tile 256x64 = 2048 slots. slot s: row=s>>3, chunk=s&7,
  // global chunk = chunk ^ (row&7).
  const int row0 = tid >> 3;
  const int ch0  = (tid & 7) ^ (row0 & 7);
  const __hip_bfloat16* aSrc = Abase + (size_t)row0 * CDIM + ch0 * 8;
  const __hip_bfloat16* bSrc = Bbase + (size_t)row0 * CDIM + ch0 * 8;

  // fragment read offsets (swizzled)
  const int wm = w >> 2, wn = w & 3;
  const int fr = lane & 15, fg = lane >> 4;
  const int offs0 = fr * 64 + ((fg ^ (fr & 7)) << 3);        // ksub 0
  const int offs1 = fr * 64 + (((fg + 4) ^ (fr & 7)) << 3);  // ksub 1
  const int aoffs0 = wm * 4096 + offs0;
  const int aoffs1 = wm * 4096 + offs1;
  const int boffs0 = 8192 + wn * 4096 + offs0;
  const int boffs1 = 8192 + wn * 4096 + offs1;

  auto SA_ = [&](int buf, int t) {
    __hip_bfloat16* dp = &sm[buf + tid * 8];
    gload_lds16(aSrc + t * 64, dp);
    gload_lds16(aSrc + (size_t)64 * CDIM + t * 64, dp + 4096);
  };
  auto SB0 = [&](int buf, int t) {
    __hip_bfloat16* dp = &sm[buf + 8192 + tid * 8];
    gload_lds16(bSrc + t * 64, dp);
    gload_lds16(bSrc + (size_t)64 * CDIM + t * 64, dp + 4096);
  };
  auto SB1 = [&](int buf, int t) {
    __hip_bfloat16* dp = &sm[buf + 8192 + 8192 + tid * 8];
    gload_lds16(bSrc + (size_t)128 * CDIM + t * 64, dp);
    gload_lds16(bSrc + (size_t)192 * CDIM + t * 64, dp + 4096);
  };

  f32x4 acc[4][4] = {};
  short8 Af[4], Ap[4], B0[2], B1[2], B0p[2], B1p[2];

#define LDA4(dst, base)                                                  \
  _Pragma("unroll") for (int i_ = 0; i_ < 4; ++i_)                       \
    dst[i_] = *(const short8*)&sm[(base) + i_ * 1024];
#define LDB2(dst, base, j0)                                              \
  _Pragma("unroll") for (int j_ = 0; j_ < 2; ++j_)                       \
    dst[j_] = *(const short8*)&sm[(base) + ((j0) + j_) * 1024];

#define MFMA_G(joff, Aset, Bset)                                         \
  __builtin_amdgcn_s_setprio(1);                                         \
  _Pragma("unroll") for (int i_ = 0; i_ < 4; ++i_)                       \
  _Pragma("unroll") for (int j_ = 0; j_ < 2; ++j_)                       \
    acc[i_][j_ + joff] = __builtin_amdgcn_mfma_f32_16x16x32_bf16(        \
        Aset[i_], Bset[j_], acc[i_][j_ + joff], 0, 0, 0);                \
  __builtin_amdgcn_s_setprio(0);

  // ---- prologue: stage tiles 0,1 into ring slots 0,1; read t0 ks0 frags ----
  SA_(0, 0); SB0(0, 0); SB1(0, 0);
  SA_(24576, 1); SB0(24576, 1); SB1(24576, 1);
  asm volatile("s_waitcnt vmcnt(6)" ::: "memory");
  SB();
  __builtin_amdgcn_s_barrier();
  SB();
  LDA4(Af, 0 + aoffs0);
  LDB2(B0, 0 + boffs0, 0);
  LDB2(B1, 0 + boffs0, 2);
  SB();

  int oc = 0, on = 24576, os = 49152;
  for (int t = 0; t < NKT; ++t) {
    // g0: ks0 j01; refill B0p <- ks1(oc)
    MFMA_G(0, Af, B0); SB();
    LDB2(B0p, oc + boffs1, 0); SB();
    // g1: ks0 j23; refill Ap <- ks1(oc); stage A(t+2) -> os
    MFMA_G(2, Af, B1); SB();
    LDA4(Ap, oc + aoffs1);
    if (t + 2 < NKT) SA_(os, t + 2);
    SB();
    // g2: ks1 j01; refill B1p <- ks1(oc); stage B0(t+2) -> os
    MFMA_G(0, Ap, B0p); SB();
    LDB2(B1p, oc + boffs1, 2);
    if (t + 2 < NKT) SB0(os, t + 2);
    SB();
    // mid-tile sync: t+1's staging landed (4 newer stage-loads outstanding);
    // lgkmcnt(0) so B1p (consumed after barrier) completes before any rewrite.
    if (t + 1 < NKT) {
      if (t + 2 < NKT) { asm volatile("s_waitcnt vmcnt(4) lgkmcnt(0)" ::: "memory"); }
      else             { asm volatile("s_waitcnt vmcnt(0) lgkmcnt(0)" ::: "memory"); }
      SB();
      __builtin_amdgcn_s_barrier();
      SB();
    }
    // g3: ks1 j23; stage B1(t+2) -> os; read t+1 ks0 frags (on) under MFMA
    MFMA_G(2, Ap, B1p); SB();
    if (t + 2 < NKT) SB1(os, t + 2);
    if (t + 1 < NKT) {
      LDA4(Af, on + aoffs0);
      LDB2(B0, on + boffs0, 0);
      LDB2(B1, on + boffs0, 2);
    }
    SB();
    const int tmp = oc; oc = on; on = os; os = tmp;
  }

  // epilogue: BN (folded) + ReLU, direct bf16 stores (write-ideal, R7).
  // C/D layout: col = lane&15, row = (lane>>4)*4 + reg  [m89 verified]
  const float* gh = gp + h * CDIM;
  const float* bh = bp + h * CDIM;
  const float* mh = mp + h * CDIM;
  const float* vh = vp + h * CDIM;
  const int colBase = nt * 256 + wn * 64 + fr;
  const int rowBase = mt * 128 + wm * 64 + fg * 4;
#pragma unroll
  for (int j = 0; j < 4; ++j) {
    const int col = colBase + j * 16;
    const float sc = gh[col] / sqrtf(vh[col] + BN_EPS);
    const float sh = bh[col] - mh[col] * sc;
#pragma unroll
    for (int i = 0; i < 4; ++i) {
      const int row = rowBase + i * 16;
#pragma unroll
      for (int rr = 0; rr < 4; ++rr) {
        float val = acc[i][j][rr] * sc + sh;
        val = val > 0.f ? val : 0.f;
        out[((size_t)h * MROWS + row + rr) * CDIM + col] = __float2bfloat16(val);
      }
    }
  }
}

// ---------------------------------------------------------------------------
// Pack final-layer weights into bf16 Wfb[3][16][2048], zero-padded.
// ---------------------------------------------------------------------------
__global__ __launch_bounds__(256) void pack_wf(
    const float* __restrict__ Wf0, const float* __restrict__ Wf1,
    const float* __restrict__ Wf2, __hip_bfloat16* __restrict__ Wfb) {
  int idx = blockIdx.x * 256 + threadIdx.x;   // 3*16*2048 = 98304
  if (idx >= 3 * 16 * CDIM) return;
  int h = idx / (16 * CDIM);
  int rem = idx - h * 16 * CDIM;
  int j = rem / CDIM;
  int k = rem - j * CDIM;
  float v = 0.f;
  if (h == 0)            v = Wf0[j * CDIM + k];
  else if (h == 1)       { if (j < 5) v = Wf1[j * CDIM + k]; }
  else                   { if (j < 5) v = Wf2[j * CDIM + k]; }
  Wfb[idx] = __float2bfloat16(v);
}

// ---------------------------------------------------------------------------
// Final 1x1 convs via MFMA, K-split 8 ways across waves.
// ---------------------------------------------------------------------------
__global__ __launch_bounds__(512) void final_mfma(
    const __hip_bfloat16* __restrict__ act,   // [3][4096][2048]
    const __hip_bfloat16* __restrict__ Wfb,   // [3][16][2048]
    const float* __restrict__ bf0, const float* __restrict__ bf1,
    const float* __restrict__ bf2, float* __restrict__ out)  // [4096][26]
{
  __shared__ float red[8][3][256];
  const int tid  = threadIdx.x;
  const int w    = tid >> 6;
  const int lane = tid & 63;
  const int r0   = blockIdx.x * 16;
  const int fr   = lane & 15;
  const int fk   = (lane >> 4) * 8;
  const int kbase = w * 256 + fk;

  f32x4 acc[3] = {};
  const __hip_bfloat16* aRow = act + (size_t)(r0 + fr) * CDIM + kbase;
  const __hip_bfloat16* bRow = Wfb + (size_t)fr * CDIM + kbase;
#pragma unroll
  for (int ks = 0; ks < 8; ++ks) {
    const int k = ks * 32;
#pragma unroll
    for (int h = 0; h < 3; ++h) {
      short8 a = *(const short8*)(aRow + (size_t)h * MROWS * CDIM + k);
      short8 b = *(const short8*)(bRow + h * 16 * CDIM + k);
      acc[h] = __builtin_amdgcn_mfma_f32_16x16x32_bf16(a, b, acc[h], 0, 0, 0);
    }
  }

  const int rb = (lane >> 4) * 4;
#pragma unroll
  for (int h = 0; h < 3; ++h)
#pragma unroll
    for (int r = 0; r < 4; ++r)
      red[w][h][(rb + r) * 16 + fr] = acc[h][r];
  __syncthreads();

  for (int e = tid; e < 768; e += 512) {
    const int h = e >> 8, idx = e & 255;
    const int row = idx >> 4, col = idx & 15;
    float s = 0.f;
#pragma unroll
    for (int w2 = 0; w2 < 8; ++w2) s += red[w2][h][idx];
    float* orow = out + (size_t)(r0 + row) * 26;
    if (h == 0)                 orow[col]      = s + bf0[col];
    else if (h == 1) { if (col < 5) orow[16 + col] = s + bf1[col]; }
    else             { if (col < 5) orow[21 + col] = s + bf2[col]; }
  }
}

// ---------------------------------------------------------------------------
extern "C" void kernel_launch(void* const* d_in, const int* in_sizes, int n_in,
                              void* d_out, int out_size, void* d_ws, size_t ws_size,
                              hipStream_t stream) {
  const float* feat = (const float*)d_in[0];
  const float* W1 = (const float*)d_in[1];
  const float* g1 = (const float*)d_in[2];
  const float* b1 = (const float*)d_in[3];
  const float* m1 = (const float*)d_in[4];
  const float* v1 = (const float*)d_in[5];
  const float* W2 = (const float*)d_in[6];
  const float* g2 = (const float*)d_in[7];
  const float* b2 = (const float*)d_in[8];
  const float* m2 = (const float*)d_in[9];
  const float* v2 = (const float*)d_in[10];
  const float* W3 = (const float*)d_in[11];
  const float* g3 = (const float*)d_in[12];
  const float* b3 = (const float*)d_in[13];
  const float* m3 = (const float*)d_in[14];
  const float* v3 = (const float*)d_in[15];
  const float* Wf0 = (const float*)d_in[16];
  const float* bf0 = (const float*)d_in[17];
  const float* Wf1 = (const float*)d_in[18];
  const float* bf1 = (const float*)d_in[19];
  const float* Wf2 = (const float*)d_in[20];
  const float* bf2 = (const float*)d_in[21];
  float* out = (float*)d_out;

  // workspace: wbuf 24MB | actA 48MB | actB 48MB (features bf16 overlaps actB)
  // Wfb (192KB) reuses wbuf after gemm3 has consumed W3.
  char* ws = (char*)d_ws;
  __hip_bfloat16* wbuf = (__hip_bfloat16*)ws;
  __hip_bfloat16* actA = (__hip_bfloat16*)(ws + 25165824);
  __hip_bfloat16* actB = (__hip_bfloat16*)(ws + 25165824 + 50331648);
  __hip_bfloat16* xb   = actB;
  __hip_bfloat16* Wfb  = wbuf;

  const int nW4 = (3 * CDIM * CDIM) / 4;
  const int nX4 = (MROWS * CDIM) / 4;
  const long long hstride = (long long)MROWS * CDIM;

  cvt2_f32_bf16<<<2048, 256, 0, stream>>>(feat, (unsigned short*)xb, nX4,
                                          W1, (unsigned short*)wbuf, nW4);
  gemm128_ring<<<768, 512, 0, stream>>>(xb, 0LL, wbuf, g1, b1, m1, v1, actA);

  cvt_f32_bf16<<<2048, 256, 0, stream>>>(W2, (unsigned short*)wbuf, nW4);
  gemm128_ring<<<768, 512, 0, stream>>>(actA, hstride, wbuf, g2, b2, m2, v2, actB);

  cvt_f32_bf16<<<2048, 256, 0, stream>>>(W3, (unsigned short*)wbuf, nW4);
  gemm128_ring<<<768, 512, 0, stream>>>(actB, hstride, wbuf, g3, b3, m3, v3, actA);

  pack_wf<<<384, 256, 0, stream>>>(Wf0, Wf1, Wf2, Wfb);
  final_mfma<<<256, 512, 0, stream>>>(actA, Wfb, bf0, bf1, bf2, out);
}

// Round 12
// 353.578 us; speedup vs baseline: 1.9945x; 1.0044x over previous
//
#include <hip/hip_runtime.h>
#include <hip/hip_bf16.h>

typedef __attribute__((ext_vector_type(8))) short short8;
typedef __attribute__((ext_vector_type(4))) float f32x4;

#define BN_EPS 1e-5f
#define MROWS 4096
#define CDIM 2048
#define NKT 32   // K tiles of 64

#define SB() __builtin_amdgcn_sched_barrier(0)

__device__ __forceinline__ void gload_lds16(const void* g, void* l) {
  __builtin_amdgcn_global_load_lds(
      (const __attribute__((address_space(1))) void*)g,
      (__attribute__((address_space(3))) void*)l, 16, 0, 0);
}

__device__ __forceinline__ unsigned short bf16u(float x) {
  __hip_bfloat16 h = __float2bfloat16(x);
  return *(unsigned short*)&h;
}
__device__ __forceinline__ short8 cvt8(float4 a, float4 b) {
  short8 r;
  r[0] = (short)bf16u(a.x); r[1] = (short)bf16u(a.y);
  r[2] = (short)bf16u(a.z); r[3] = (short)bf16u(a.w);
  r[4] = (short)bf16u(b.x); r[5] = (short)bf16u(b.y);
  r[6] = (short)bf16u(b.z); r[7] = (short)bf16u(b.w);
  return r;
}

// ---------------------------------------------------------------------------
// fp32 -> bf16 conversion (vectorized float4 -> ushort4)
// ---------------------------------------------------------------------------
__global__ __launch_bounds__(256) void cvt_f32_bf16(const float* __restrict__ in,
                                                    unsigned short* __restrict__ out,
                                                    int n4) {
  int idx = blockIdx.x * blockDim.x + threadIdx.x;
  int stride = gridDim.x * blockDim.x;
  for (int i = idx; i < n4; i += stride) {
    float4 vv = ((const float4*)in)[i];
    ushort4 o;
    o.x = bf16u(vv.x); o.y = bf16u(vv.y); o.z = bf16u(vv.z); o.w = bf16u(vv.w);
    ((ushort4*)out)[i] = o;
  }
}

// Two-tensor variant: converts feat and W1 in a single launch.
__global__ __launch_bounds__(256) void cvt2_f32_bf16(
    const float* __restrict__ inA, unsigned short* __restrict__ outA, int nA4,
    const float* __restrict__ inB, unsigned short* __restrict__ outB, int nB4) {
  int idx = blockIdx.x * blockDim.x + threadIdx.x;
  int stride = gridDim.x * blockDim.x;
  int tot = nA4 + nB4;
  for (int i = idx; i < tot; i += stride) {
    const float4* src; ushort4* dst; int k;
    if (i < nA4) { src = (const float4*)inA; dst = (ushort4*)outA; k = i; }
    else         { src = (const float4*)inB; dst = (ushort4*)outB; k = i - nA4; }
    float4 vv = src[k];
    ushort4 o;
    o.x = bf16u(vv.x); o.y = bf16u(vv.y); o.z = bf16u(vv.z); o.w = bf16u(vv.w);
    dst[k] = o;
  }
}

// ---------------------------------------------------------------------------
// 128x256 tile, BK=64, 3-deep LDS ring (144 KiB, 1 block/CU), grid 768 = 3
// exact rounds. 8 waves (2M x 4N) of 64x64, acc[4][4]. R7 schedule:
// tile t+1's ks0 fragment reads issue UNDER tile t's last MFMA group; one
// {vmcnt lgkmcnt(0)} + barrier per K-tile (mid-tile).
// R12: next-layer W fp32->bf16 conversion embedded in the epilogue — grid
// 768 == (3*2048*2048/4)/4096, so block b converts float4s [b*4096,
// b*4096+4096) (8/thread). Loads issue right after the K-loop (vmcnt==0
// there: all counted waits retired), hide under BN/C-store epilogue,
// stores at the end. GEMM HBM util is 22% -> conversion traffic rides free.
// Swizzle chunk^=(row&7) on 16B chunks (R3/R6-verified, 0 conflicts).
// out[h][m][d] = relu((sum_c A[h][m][c]*W[h][d][c])*scale + shift)
// ---------------------------------------------------------------------------
__global__ __launch_bounds__(512, 2) void gemm128_ring(
    const __hip_bfloat16* __restrict__ A, long long a_hstride,
    const __hip_bfloat16* __restrict__ W,
    const float* __restrict__ gp, const float* __restrict__ bp,
    const float* __restrict__ mp, const float* __restrict__ vp,
    __hip_bfloat16* __restrict__ out,
    const float* __restrict__ cvtSrc, unsigned short* __restrict__ cvtDst)
{
  __shared__ __hip_bfloat16 sm[73728];   // 144 KiB = 3 x 24576 elems

  const int tid  = threadIdx.x;
  const int w    = tid >> 6;
  const int lane = tid & 63;

  // XCD-bijective swizzle over 768 blocks (768 % 8 == 0, q = 96)
  const int bid = blockIdx.x;
  const int swz = (bid & 7) * 96 + (bid >> 3);
  const int h   = swz >> 8;          // 256 tiles per head
  const int rem = swz & 255;
  const int mt  = rem >> 3;          // 32 m-tiles of 128
  const int nt  = rem & 7;           // 8 n-tiles of 256

  const __hip_bfloat16* Abase = A + (size_t)h * (size_t)a_hstride + (size_t)(mt * 128) * CDIM;
  const __hip_bfloat16* Bbase = W + ((size_t)h * CDIM + (size_t)(nt * 256)) * CDIM;

  // staging: A tile 128x64 = 1024 16B slots (thread t: slots t, t+512);
  // B tile 256x64 = 2048 slots. slot s: row=s>>3, chunk=s&7,
  // global chunk = chunk ^ (row&7).
  const int row0 = tid >> 3;
  const int ch0  = (tid & 7) ^ (row0 & 7);
  const __hip_bfloat16* aSrc = Abase + (size_t)row0 * CDIM + ch0 * 8;
  const __hip_bfloat16* bSrc = Bbase + (size_t)row0 * CDIM + ch0 * 8;

  // fragment read offsets (swizzled)
  const int wm = w >> 2, wn = w & 3;
  const int fr = lane & 15, fg = lane >> 4;
  const int offs0 = fr * 64 + ((fg ^ (fr & 7)) << 3);        // ksub 0
  const int offs1 = fr * 64 + (((fg + 4) ^ (fr & 7)) << 3);  // ksub 1
  const int aoffs0 = wm * 4096 + offs0;
  const int aoffs1 = wm * 4096 + offs1;
  const int boffs0 = 8192 + wn * 4096 + offs0;
  const int boffs1 = 8192 + wn * 4096 + offs1;

  auto SA_ = [&](int buf, int t) {
    __hip_bfloat16* dp = &sm[buf + tid * 8];
    gload_lds16(aSrc + t * 64, dp);
    gload_lds16(aSrc + (size_t)64 * CDIM + t * 64, dp + 4096);
  };
  auto SB0 = [&](int buf, int t) {
    __hip_bfloat16* dp = &sm[buf + 8192 + tid * 8];
    gload_lds16(bSrc + t * 64, dp);
    gload_lds16(bSrc + (size_t)64 * CDIM + t * 64, dp + 4096);
  };
  auto SB1 = [&](int buf, int t) {
    __hip_bfloat16* dp = &sm[buf + 8192 + 8192 + tid * 8];
    gload_lds16(bSrc + (size_t)128 * CDIM + t * 64, dp);
    gload_lds16(bSrc + (size_t)192 * CDIM + t * 64, dp + 4096);
  };

  f32x4 acc[4][4] = {};
  short8 Af[4], Ap[4], B0[2], B1[2], B0p[2], B1p[2];

#define LDA4(dst, base)                                                  \
  _Pragma("unroll") for (int i_ = 0; i_ < 4; ++i_)                       \
    dst[i_] = *(const short8*)&sm[(base) + i_ * 1024];
#define LDB2(dst, base, j0)                                              \
  _Pragma("unroll") for (int j_ = 0; j_ < 2; ++j_)                       \
    dst[j_] = *(const short8*)&sm[(base) + ((j0) + j_) * 1024];

#define MFMA_G(joff, Aset, Bset)                                         \
  __builtin_amdgcn_s_setprio(1);                                         \
  _Pragma("unroll") for (int i_ = 0; i_ < 4; ++i_)                       \
  _Pragma("unroll") for (int j_ = 0; j_ < 2; ++j_)                       \
    acc[i_][j_ + joff] = __builtin_amdgcn_mfma_f32_16x16x32_bf16(        \
        Aset[i_], Bset[j_], acc[i_][j_ + joff], 0, 0, 0);                \
  __builtin_amdgcn_s_setprio(0);

  // ---- prologue: stage tiles 0,1 into ring slots 0,1; read t0 ks0 frags ----
  SA_(0, 0); SB0(0, 0); SB1(0, 0);
  SA_(24576, 1); SB0(24576, 1); SB1(24576, 1);
  asm volatile("s_waitcnt vmcnt(6)" ::: "memory");
  SB();
  __builtin_amdgcn_s_barrier();
  SB();
  LDA4(Af, 0 + aoffs0);
  LDB2(B0, 0 + boffs0, 0);
  LDB2(B1, 0 + boffs0, 2);
  SB();

  int oc = 0, on = 24576, os = 49152;
  for (int t = 0; t < NKT; ++t) {
    // g0: ks0 j01; refill B0p <- ks1(oc)
    MFMA_G(0, Af, B0); SB();
    LDB2(B0p, oc + boffs1, 0); SB();
    // g1: ks0 j23; refill Ap <- ks1(oc); stage A(t+2) -> os
    MFMA_G(2, Af, B1); SB();
    LDA4(Ap, oc + aoffs1);
    if (t + 2 < NKT) SA_(os, t + 2);
    SB();
    // g2: ks1 j01; refill B1p <- ks1(oc); stage B0(t+2) -> os
    MFMA_G(0, Ap, B0p); SB();
    LDB2(B1p, oc + boffs1, 2);
    if (t + 2 < NKT) SB0(os, t + 2);
    SB();
    // mid-tile sync: t+1's staging landed (4 newer stage-loads outstanding);
    // lgkmcnt(0) so B1p (consumed after barrier) completes before any rewrite.
    if (t + 1 < NKT) {
      if (t + 2 < NKT) { asm volatile("s_waitcnt vmcnt(4) lgkmcnt(0)" ::: "memory"); }
      else             { asm volatile("s_waitcnt vmcnt(0) lgkmcnt(0)" ::: "memory"); }
      SB();
      __builtin_amdgcn_s_barrier();
      SB();
    }
    // g3: ks1 j23; stage B1(t+2) -> os; read t+1 ks0 frags (on) under MFMA
    MFMA_G(2, Ap, B1p); SB();
    if (t + 2 < NKT) SB1(os, t + 2);
    if (t + 1 < NKT) {
      LDA4(Af, on + aoffs0);
      LDB2(B0, on + boffs0, 0);
      LDB2(B1, on + boffs0, 2);
    }
    SB();
    const int tmp = oc; oc = on; on = os; os = tmp;
  }

  // ---- embedded next-layer W conversion: issue loads (vmcnt clean here) ----
  float4 cw[8];
  if (cvtSrc) {
    const float4* csrc = (const float4*)cvtSrc + (size_t)bid * 4096 + tid;
#pragma unroll
    for (int q = 0; q < 8; ++q) cw[q] = csrc[q * 512];
  }
  SB();

  // epilogue: BN (folded) + ReLU, direct bf16 stores (write-ideal, R7).
  // C/D layout: col = lane&15, row = (lane>>4)*4 + reg  [m89 verified]
  const float* gh = gp + h * CDIM;
  const float* bh = bp + h * CDIM;
  const float* mh = mp + h * CDIM;
  const float* vh = vp + h * CDIM;
  const int colBase = nt * 256 + wn * 64 + fr;
  const int rowBase = mt * 128 + wm * 64 + fg * 4;
#pragma unroll
  for (int j = 0; j < 4; ++j) {
    const int col = colBase + j * 16;
    const float sc = gh[col] / sqrtf(vh[col] + BN_EPS);
    const float sh = bh[col] - mh[col] * sc;
#pragma unroll
    for (int i = 0; i < 4; ++i) {
      const int row = rowBase + i * 16;
#pragma unroll
      for (int rr = 0; rr < 4; ++rr) {
        float val = acc[i][j][rr] * sc + sh;
        val = val > 0.f ? val : 0.f;
        out[((size_t)h * MROWS + row + rr) * CDIM + col] = __float2bfloat16(val);
      }
    }
  }

  // ---- embedded conversion: cvt + store ----
  if (cvtSrc) {
    ushort4* cdst = (ushort4*)cvtDst + (size_t)bid * 4096 + tid;
#pragma unroll
    for (int q = 0; q < 8; ++q) {
      float4 v = cw[q];
      ushort4 o;
      o.x = bf16u(v.x); o.y = bf16u(v.y); o.z = bf16u(v.z); o.w = bf16u(v.w);
      cdst[q * 512] = o;
    }
  }
}

// ---------------------------------------------------------------------------
// Final 1x1 convs via MFMA, K-split 8 ways across waves. Reads RAW fp32
// final weights (rows >=5 of heads 1/2 are implicit zeros) — no pack pass.
// ---------------------------------------------------------------------------
__global__ __launch_bounds__(512) void final_mfma_raw(
    const __hip_bfloat16* __restrict__ act,   // [3][4096][2048]
    const float* __restrict__ Wf0, const float* __restrict__ bf0,
    const float* __restrict__ Wf1, const float* __restrict__ bf1,
    const float* __restrict__ Wf2, const float* __restrict__ bf2,
    float* __restrict__ out)                   // [4096][26]
{
  __shared__ float red[8][3][256];
  const int tid  = threadIdx.x;
  const int w    = tid >> 6;
  const int lane = tid & 63;
  const int r0   = blockIdx.x * 16;
  const int fr   = lane & 15;
  const int fk   = (lane >> 4) * 8;
  const int kbase = w * 256 + fk;

  f32x4 acc[3] = {};
  const __hip_bfloat16* aRow = act + (size_t)(r0 + fr) * CDIM + kbase;
  const float* w0p = Wf0 + (size_t)fr * CDIM + kbase;
  const float* w1p = Wf1 + (size_t)fr * CDIM + kbase;
  const float* w2p = Wf2 + (size_t)fr * CDIM + kbase;
  const short8 zro = {0, 0, 0, 0, 0, 0, 0, 0};
#pragma unroll
  for (int ks = 0; ks < 8; ++ks) {
    const int k = ks * 32;
    {
      short8 a = *(const short8*)(aRow + k);
      short8 b = cvt8(*(const float4*)(w0p + k), *(const float4*)(w0p + k + 4));
      acc[0] = __builtin_amdgcn_mfma_f32_16x16x32_bf16(a, b, acc[0], 0, 0, 0);
    }
    {
      short8 a = *(const short8*)(aRow + (size_t)MROWS * CDIM + k);
      short8 b = zro;
      if (fr < 5) b = cvt8(*(const float4*)(w1p + k), *(const float4*)(w1p + k + 4));
      acc[1] = __builtin_amdgcn_mfma_f32_16x16x32_bf16(a, b, acc[1], 0, 0, 0);
    }
    {
      short8 a = *(const short8*)(aRow + (size_t)2 * MROWS * CDIM + k);
      short8 b = zro;
      if (fr < 5) b = cvt8(*(const float4*)(w2p + k), *(const float4*)(w2p + k + 4));
      acc[2] = __builtin_amdgcn_mfma_f32_16x16x32_bf16(a, b, acc[2], 0, 0, 0);
    }
  }

  const int rb = (lane >> 4) * 4;
#pragma unroll
  for (int h = 0; h < 3; ++h)
#pragma unroll
    for (int r = 0; r < 4; ++r)
      red[w][h][(rb + r) * 16 + fr] = acc[h][r];
  __syncthreads();

  for (int e = tid; e < 768; e += 512) {
    const int h = e >> 8, idx = e & 255;
    const int row = idx >> 4, col = idx & 15;
    float s = 0.f;
#pragma unroll
    for (int w2 = 0; w2 < 8; ++w2) s += red[w2][h][idx];
    float* orow = out + (size_t)(r0 + row) * 26;
    if (h == 0)                 orow[col]      = s + bf0[col];
    else if (h == 1) { if (col < 5) orow[16 + col] = s + bf1[col]; }
    else             { if (col < 5) orow[21 + col] = s + bf2[col]; }
  }
}

// ---------------------------------------------------------------------------
extern "C" void kernel_launch(void* const* d_in, const int* in_sizes, int n_in,
                              void* d_out, int out_size, void* d_ws, size_t ws_size,
                              hipStream_t stream) {
  const float* feat = (const float*)d_in[0];
  const float* W1 = (const float*)d_in[1];
  const float* g1 = (const float*)d_in[2];
  const float* b1 = (const float*)d_in[3];
  const float* m1 = (const float*)d_in[4];
  const float* v1 = (const float*)d_in[5];
  const float* W2 = (const float*)d_in[6];
  const float* g2 = (const float*)d_in[7];
  const float* b2 = (const float*)d_in[8];
  const float* m2 = (const float*)d_in[9];
  const float* v2 = (const float*)d_in[10];
  const float* W3 = (const float*)d_in[11];
  const float* g3 = (const float*)d_in[12];
  const float* b3 = (const float*)d_in[13];
  const float* m3 = (const float*)d_in[14];
  const float* v3 = (const float*)d_in[15];
  const float* Wf0 = (const float*)d_in[16];
  const float* bf0 = (const float*)d_in[17];
  const float* Wf1 = (const float*)d_in[18];
  const float* bf1 = (const float*)d_in[19];
  const float* Wf2 = (const float*)d_in[20];
  const float* bf2 = (const float*)d_in[21];
  float* out = (float*)d_out;

  const size_t WB = 25165824;    // 24 MiB (bf16 weights, one layer)
  const size_t AB = 50331648;    // 48 MiB (bf16 activations, 3 heads)
  const int nW4 = (3 * CDIM * CDIM) / 4;
  const int nX4 = (MROWS * CDIM) / 4;
  const long long hstride = (long long)MROWS * CDIM;
  char* ws = (char*)d_ws;

  __hip_bfloat16* actA;

  if (ws_size >= 2 * WB + 2 * AB) {
    // fast path: ping-pong weight buffers; W2/W3 conversion embedded in gemms.
    __hip_bfloat16* wbufA = (__hip_bfloat16*)ws;
    __hip_bfloat16* wbufB = (__hip_bfloat16*)(ws + WB);
    actA                  = (__hip_bfloat16*)(ws + 2 * WB);
    __hip_bfloat16* actB  = (__hip_bfloat16*)(ws + 2 * WB + AB);
    __hip_bfloat16* xb    = actB;

    cvt2_f32_bf16<<<2048, 256, 0, stream>>>(feat, (unsigned short*)xb, nX4,
                                            W1, (unsigned short*)wbufA, nW4);
    gemm128_ring<<<768, 512, 0, stream>>>(xb, 0LL, wbufA, g1, b1, m1, v1, actA,
                                          W2, (unsigned short*)wbufB);
    gemm128_ring<<<768, 512, 0, stream>>>(actA, hstride, wbufB, g2, b2, m2, v2, actB,
                                          W3, (unsigned short*)wbufA);
    gemm128_ring<<<768, 512, 0, stream>>>(actB, hstride, wbufA, g3, b3, m3, v3, actA,
                                          nullptr, nullptr);
  } else {
    // fallback (R11 path): single weight buffer, standalone conversions.
    __hip_bfloat16* wbuf = (__hip_bfloat16*)ws;
    actA                 = (__hip_bfloat16*)(ws + WB);
    __hip_bfloat16* actB = (__hip_bfloat16*)(ws + WB + AB);
    __hip_bfloat16* xb   = actB;

    cvt2_f32_bf16<<<2048, 256, 0, stream>>>(feat, (unsigned short*)xb, nX4,
                                            W1, (unsigned short*)wbuf, nW4);
    gemm128_ring<<<768, 512, 0, stream>>>(xb, 0LL, wbuf, g1, b1, m1, v1, actA,
                                          nullptr, nullptr);
    cvt_f32_bf16<<<2048, 256, 0, stream>>>(W2, (unsigned short*)wbuf, nW4);
    gemm128_ring<<<768, 512, 0, stream>>>(actA, hstride, wbuf, g2, b2, m2, v2, actB,
                                          nullptr, nullptr);
    cvt_f32_bf16<<<2048, 256, 0, stream>>>(W3, (unsigned short*)wbuf, nW4);
    gemm128_ring<<<768, 512, 0, stream>>>(actB, hstride, wbuf, g3, b3, m3, v3, actA,
                                          nullptr, nullptr);
  }

  final_mfma_raw<<<256, 512, 0, stream>>>(actA, Wf0, bf0, Wf1, bf1, Wf2, bf2, out);
}